// Round 1
// baseline (809.224 us; speedup 1.0000x reference)
//
#include <hip/hip_runtime.h>
#include <math.h>

// Laminography forward projector, fully fused pipeline:
//  (1) centered 3D FFT of complex volume (3 1D passes into d_ws)
//  (2) trilinear Fourier-slice sampling -> d_out (as float2)
//  (3) centered inverse 2D FFT, two in-place passes on d_out
// Centered transform identity (n=256, n/2 even):
//  F[k] = (-1)^k * FFT[ (-1)^x * u[x] ]   per axis, forward and inverse alike.

namespace {

// -------- contiguous-axis pass (MODE 0): 8 lines/block, coalesce along j ----
template<bool INV>
__global__ __launch_bounds__(256)
void fft_pass0(const float2* in, float2* out) {
  __shared__ float sre[8][265];
  __shared__ float sim[8][265];
  __shared__ float twr[128];
  __shared__ float twi[128];
  const int t = threadIdx.x;
  if (t < 128) {
    const float TWO_PI = 6.28318530717958647692f;
    float ang = (INV ? TWO_PI : -TWO_PI) * ((float)t * (1.0f / 256.0f));
    float s, c;
    sincosf(ang, &s, &c);
    twr[t] = c;
    twi[t] = s;
  }
  const int l = t >> 5;        // line within block
  const int j0 = t & 31;       // coalesce along j (contiguous axis)
  const int lineIdx = (int)blockIdx.x * 8 + l;
  const int base = lineIdx * 256;

  #pragma unroll
  for (int r = 0; r < 8; r++) {
    int j = j0 + 32 * r;
    float2 v = in[base + j];
    float sgn = (j & 1) ? -1.0f : 1.0f;
    sre[l][j] = v.x * sgn;
    sim[l][j] = v.y * sgn;
  }
  __syncthreads();

  const int line = t >> 5;
  const int lane = t & 31;
  #pragma unroll
  for (int s = 0; s < 8; s++) {
    const int half = 128 >> s;
    #pragma unroll
    for (int r = 0; r < 4; r++) {
      int b   = lane + 32 * r;
      int pos = b & (half - 1);
      int grp = b >> (7 - s);
      int i   = (grp << (8 - s)) + pos;
      int j   = i + half;
      float ar = sre[line][i], ai = sim[line][i];
      float br = sre[line][j], bi = sim[line][j];
      sre[line][i] = ar + br;
      sim[line][i] = ai + bi;
      float dr = ar - br, di = ai - bi;
      int mm = pos << s;
      float wr = twr[mm], wi = twi[mm];
      sre[line][j] = dr * wr - di * wi;
      sim[line][j] = dr * wi + di * wr;
    }
    __syncthreads();
  }

  const float scale = INV ? (1.0f / 256.0f) : 1.0f;
  #pragma unroll
  for (int r = 0; r < 8; r++) {
    int j = j0 + 32 * r;
    int rev = (int)(__brev((unsigned)j) >> 24);
    float sgn = (j & 1) ? -scale : scale;
    float2 v;
    v.x = sre[l][rev] * sgn;
    v.y = sim[l][rev] * sgn;
    out[base + j] = v;
  }
}

// -------- strided-axis pass (MODE 1: stride 256, MODE 2: stride 65536) ------
// 16 lines/block: 16 consecutive lines x 8B = 128B fully-coalesced chunks.
template<int MODE, bool INV>
__global__ __launch_bounds__(256)
void fft_pass16(const float2* in, float2* out) {
  __shared__ float sre[16][264];   // 264 % 32 == 8 -> <=2-way conflicts in butterflies
  __shared__ float sim[16][264];
  __shared__ float twr[128];
  __shared__ float twi[128];
  const int t = threadIdx.x;
  if (t < 128) {
    const float TWO_PI = 6.28318530717958647692f;
    float ang = (INV ? TWO_PI : -TWO_PI) * ((float)t * (1.0f / 256.0f));
    float s, c;
    sincosf(ang, &s, &c);
    twr[t] = c;
    twi[t] = s;
  }
  const int l  = t & 15;     // line within block (contiguous axis) -> coalesce
  const int j0 = t >> 4;     // 0..15, each thread covers 16 j values
  const int lineIdx = (int)blockIdx.x * 16 + l;
  int base, stride;
  if (MODE == 1) { base = (lineIdx >> 8) * 65536 + (lineIdx & 255); stride = 256;   }
  else           { base = lineIdx;                                  stride = 65536; }

  #pragma unroll
  for (int r = 0; r < 16; r++) {
    int j = j0 + 16 * r;
    float2 v = in[base + j * stride];
    float sgn = (j & 1) ? -1.0f : 1.0f;
    sre[l][j] = v.x * sgn;
    sim[l][j] = v.y * sgn;
  }
  __syncthreads();

  // radix-2 DIF; 16 threads per line, 8 butterflies/thread/stage
  const int line = t >> 4;
  const int lane = t & 15;
  #pragma unroll
  for (int s = 0; s < 8; s++) {
    const int half = 128 >> s;
    #pragma unroll
    for (int r = 0; r < 8; r++) {
      int b   = lane + 16 * r;
      int pos = b & (half - 1);
      int grp = b >> (7 - s);
      int i   = (grp << (8 - s)) + pos;
      int jj  = i + half;
      float ar = sre[line][i], ai = sim[line][i];
      float br = sre[line][jj], bi = sim[line][jj];
      sre[line][i] = ar + br;
      sim[line][i] = ai + bi;
      float dr = ar - br, di = ai - bi;
      int mm = pos << s;
      float wr = twr[mm], wi = twi[mm];
      sre[line][jj] = dr * wr - di * wi;
      sim[line][jj] = dr * wi + di * wr;
    }
    __syncthreads();
  }

  const float scale = INV ? (1.0f / 256.0f) : 1.0f;
  #pragma unroll
  for (int r = 0; r < 16; r++) {
    int j = j0 + 16 * r;
    int rev = (int)(__brev((unsigned)j) >> 24);
    float sgn = (j & 1) ? -scale : scale;
    float2 v;
    v.x = sre[l][rev] * sgn;
    v.y = sim[l][rev] * sgn;
    out[base + j * stride] = v;
  }
}

// -------- Fourier-slice trilinear sampling: 4 pixels/thread along b ---------
__global__ __launch_bounds__(256)
void sample_kernel(const float2* __restrict__ F, float2* __restrict__ out,
                   const float* __restrict__ theta, const float* __restrict__ tiltp) {
  const int m  = blockIdx.z;
  const int a  = blockIdx.y * 16 + threadIdx.y;            // detector slow axis (kv)
  const int b0 = blockIdx.x * 64 + threadIdx.x * 4;        // detector fast axis (ku)
  const float th = theta[m];
  float st, ct;
  sincosf(th, &st, &ct);
  const float tl = tiltp[0];
  float sp, cp;
  sincosf(tl, &sp, &cp);

  const float av = (float)(a - 128);
  // z depends only on a -> shared across the 4 pixels
  const float p2 = av * sp + 128.0f;
  const float f2 = floorf(p2);
  const int   z0 = (int)f2;
  const float fz = p2 - f2;
  const int   z1 = z0 + 1;
  const bool vz0 = (z0 >= 0) & (z0 < 256);
  const bool vz1 = (z1 >= 0) & (z1 < 256);
  const int  zc0 = min(max(z0, 0), 255);
  const int  zc1 = min(max(z1, 0), 255);
  const float p0b = av * (-st * cp) + 128.0f;
  const float p1b = av * (ct * cp) + 128.0f;

  float2 res[4];
  #pragma unroll
  for (int i = 0; i < 4; i++) {
    const float bu = (float)(b0 + i - 128);
    const float p0 = bu * ct + p0b;
    const float p1 = bu * st + p1b;
    const float f0 = floorf(p0), f1 = floorf(p1);
    const int x0 = (int)f0, y0 = (int)f1;
    const float fx = p0 - f0, fy = p1 - f1;
    float accr = 0.0f, acci = 0.0f;
    #pragma unroll
    for (int dx = 0; dx < 2; dx++) {
      const int x = x0 + dx;
      const bool vx = (x >= 0) & (x < 256);
      const int xc = min(max(x, 0), 255);
      const float wx = dx ? fx : (1.0f - fx);
      #pragma unroll
      for (int dy = 0; dy < 2; dy++) {
        const int y = y0 + dy;
        const bool vy = vx & (y >= 0) & (y < 256);
        const int yc = min(max(y, 0), 255);
        const float wxy = wx * (dy ? fy : (1.0f - fy));
        const int rowbase = (xc * 256 + yc) * 256;
        {
          const float w0 = (vy & vz0) ? wxy * (1.0f - fz) : 0.0f;
          const float2 c = F[rowbase + zc0];
          accr += w0 * c.x; acci += w0 * c.y;
        }
        {
          const float w1 = (vy & vz1) ? wxy * fz : 0.0f;
          const float2 c = F[rowbase + zc1];
          accr += w1 * c.x; acci += w1 * c.y;
        }
      }
    }
    res[i] = make_float2(accr, acci);
  }
  // b0 is a multiple of 4 -> 32B-aligned; two float4 stores, fully coalesced
  float4* o = (float4*)(&out[((size_t)(m * 256 + a)) * 256 + b0]);
  o[0] = make_float4(res[0].x, res[0].y, res[1].x, res[1].y);
  o[1] = make_float4(res[2].x, res[2].y, res[3].x, res[3].y);
}

}  // namespace

extern "C" void kernel_launch(void* const* d_in, const int* in_sizes, int n_in,
                              void* d_out, int out_size, void* d_ws, size_t ws_size,
                              hipStream_t stream) {
  const float2* w  = (const float2*)d_in[0];   // (256,256,256,2) f32 == float2 complex
  const float*  th = (const float*)d_in[1];    // (180,)
  const float*  tl = (const float*)d_in[2];    // scalar
  float2* F    = (float2*)d_ws;                // 256^3 complex64 = 128 MiB
  float2* out2 = (float2*)d_out;               // (180,256,256) complex64 view of output

  // forward 3D FFT (centered), one pass per axis, 65536 lines each
  fft_pass0<false><<<8192, 256, 0, stream>>>(w, F);        // axis 2 (contiguous)
  fft_pass16<1, false><<<4096, 256, 0, stream>>>(F, F);    // axis 1 (stride 256)
  fft_pass16<2, false><<<4096, 256, 0, stream>>>(F, F);    // axis 0 (stride 65536)

  // Fourier-slice trilinear sampling -> d_out
  dim3 g(4, 16, 180), blk(16, 16);
  sample_kernel<<<g, blk, 0, stream>>>(F, out2, th, tl);

  // centered inverse 2D FFT per angle, in place in d_out
  fft_pass0<true><<<5760, 256, 0, stream>>>(out2, out2);   // axis b (contiguous)
  fft_pass16<1, true><<<2880, 256, 0, stream>>>(out2, out2); // axis a (stride 256)
}

// Round 2
// 637.091 us; speedup vs baseline: 1.2702x; 1.2702x over previous
//
#include <hip/hip_runtime.h>
#include <math.h>

// Laminography forward projector, fully fused pipeline:
//  (1) centered 3D FFT of complex volume (3 generic 1D passes into d_ws)
//  (2) trilinear Fourier-slice sampling -> d_out (as float2)
//  (3) centered inverse 2D FFT, two in-place passes on d_out
// Centered transform identity (n=256, n/2 even):
//  F[k] = (-1)^k * FFT[ (-1)^x * u[x] ]   per axis, forward and inverse alike.

namespace {

template<int MODE, bool INV>
__global__ __launch_bounds__(256)
void fft_pass(const float2* in, float2* out) {
  // MODE 0: contiguous lines, base = lineIdx*256,                    stride 1
  // MODE 1: base = (lineIdx>>8)*65536 + (lineIdx&255),               stride 256
  // MODE 2: base = lineIdx,                                          stride 65536
  __shared__ float sre[8][265];   // 8 lines x 256 pts, pad to dodge bank conflicts
  __shared__ float sim[8][265];
  __shared__ float twr[128];
  __shared__ float twi[128];
  const int t = threadIdx.x;
  if (t < 128) {
    const float TWO_PI = 6.28318530717958647692f;
    float ang = (INV ? TWO_PI : -TWO_PI) * ((float)t * (1.0f / 256.0f));
    float s, c;
    sincosf(ang, &s, &c);
    twr[t] = c;
    twi[t] = s;
  }
  int l, j0, base, stride;
  if (MODE == 0) { l = t >> 5; j0 = t & 31; }   // lines 256 apart: coalesce along j
  else           { l = t & 7;  j0 = t >> 3; }   // lines contiguous: coalesce along l
  const int lineIdx = (int)blockIdx.x * 8 + l;
  if (MODE == 0)      { base = lineIdx * 256;                            stride = 1;     }
  else if (MODE == 1) { base = (lineIdx >> 8) * 65536 + (lineIdx & 255); stride = 256;   }
  else                { base = lineIdx;                                  stride = 65536; }

  // load with (-1)^x pre-twiddle (centering)
  #pragma unroll
  for (int r = 0; r < 8; r++) {
    int j = j0 + 32 * r;
    float2 v = in[base + j * stride];
    float sgn = (j & 1) ? -1.0f : 1.0f;
    sre[l][j] = v.x * sgn;
    sim[l][j] = v.y * sgn;
  }
  __syncthreads();

  // radix-2 DIF, 8 stages; 32 threads per line, 4 butterflies/thread/stage
  const int line = t >> 5;
  const int lane = t & 31;
  #pragma unroll
  for (int s = 0; s < 8; s++) {
    const int half = 128 >> s;
    #pragma unroll
    for (int r = 0; r < 4; r++) {
      int b   = lane + 32 * r;
      int pos = b & (half - 1);
      int grp = b >> (7 - s);
      int i   = (grp << (8 - s)) + pos;
      int j   = i + half;
      float ar = sre[line][i], ai = sim[line][i];
      float br = sre[line][j], bi = sim[line][j];
      sre[line][i] = ar + br;
      sim[line][i] = ai + bi;
      float dr = ar - br, di = ai - bi;
      int mm = pos << s;                 // twiddle exponent, always < 128
      float wr = twr[mm], wi = twi[mm];
      sre[line][j] = dr * wr - di * wi;
      sim[line][j] = dr * wi + di * wr;
    }
    __syncthreads();
  }

  // store: DIF leaves X[bitrev(p)] at p; apply (-1)^k post-twiddle (+ 1/n for inverse)
  const float scale = INV ? (1.0f / 256.0f) : 1.0f;
  #pragma unroll
  for (int r = 0; r < 8; r++) {
    int j = j0 + 32 * r;
    int rev = (int)(__brev((unsigned)j) >> 24);
    float sgn = (j & 1) ? -scale : scale;
    float2 v;
    v.x = sre[l][rev] * sgn;
    v.y = sim[l][rev] * sgn;
    out[base + j * stride] = v;
  }
}

// Fourier-slice trilinear sampling.
// Gather address = (x*256+y)*256+z with z = av*sin(tilt)+128: the memory-
// contiguous axis z tracks the detector 'a' axis (step ~0.84 elem/pixel),
// while the 'b' axis steps x/y by ~1/pixel (512KB / 2KB address jumps).
// So fast lanes run along a (threadIdx.x = a_local) to maximize cacheline
// sharing within a wave's gathers; stores are transposed through LDS to
// stay coalesced along b.
__global__ __launch_bounds__(256)
void sample_kernel(const float2* __restrict__ F, float2* __restrict__ out,
                   const float* __restrict__ theta, const float* __restrict__ tiltp) {
  __shared__ float2 tile[16][18];   // [b_local][a_local], padded
  const int m  = blockIdx.z;
  const int tx = threadIdx.x;
  const int ty = threadIdx.y;
  const int a = blockIdx.x * 16 + tx;   // detector slow axis (kv) -> fast lanes
  const int b = blockIdx.y * 16 + ty;   // detector fast axis (ku)
  float th = theta[m];
  float st, ct;
  sincosf(th, &st, &ct);
  float tl = tiltp[0];
  float sp, cp;
  sincosf(tl, &sp, &cp);
  float bu = (float)(b - 128);
  float av = (float)(a - 128);
  // pos = bu*e_u + av*e_v + 128, e_u=(ct,st,0), e_v=(-st*cp, ct*cp, sp)
  float p0 = bu * ct + av * (-st * cp) + 128.0f;
  float p1 = bu * st + av * (ct * cp) + 128.0f;
  float p2 = av * sp + 128.0f;
  float f0 = floorf(p0), f1 = floorf(p1), f2 = floorf(p2);
  int x0 = (int)f0, y0 = (int)f1, z0 = (int)f2;
  float fx = p0 - f0, fy = p1 - f1, fz = p2 - f2;
  float accr = 0.0f, acci = 0.0f;
  #pragma unroll
  for (int dx = 0; dx < 2; dx++) {
    int x = x0 + dx;
    bool vx = (x >= 0) && (x < 256);
    int xc = min(max(x, 0), 255);
    float wx = dx ? fx : (1.0f - fx);
    #pragma unroll
    for (int dy = 0; dy < 2; dy++) {
      int y = y0 + dy;
      bool vy = vx && (y >= 0) && (y < 256);
      int yc = min(max(y, 0), 255);
      float wxy = wx * (dy ? fy : (1.0f - fy));
      int rowbase = (xc * 256 + yc) * 256;
      #pragma unroll
      for (int dz = 0; dz < 2; dz++) {
        int z = z0 + dz;
        bool v = vy && (z >= 0) && (z < 256);
        int zc = min(max(z, 0), 255);
        float w = v ? wxy * (dz ? fz : (1.0f - fz)) : 0.0f;
        float2 c = F[rowbase + zc];   // clamped gather; masked by w
        accr += w * c.x;
        acci += w * c.y;
      }
    }
  }
  tile[ty][tx] = make_float2(accr, acci);
  __syncthreads();
  // transposed write-out: lanes (tx) now run along b -> 128B contiguous stores
  const int oa = blockIdx.x * 16 + ty;
  const int ob = blockIdx.y * 16 + tx;
  out[((size_t)m * 256 + oa) * 256 + ob] = tile[tx][ty];
}

}  // namespace

extern "C" void kernel_launch(void* const* d_in, const int* in_sizes, int n_in,
                              void* d_out, int out_size, void* d_ws, size_t ws_size,
                              hipStream_t stream) {
  const float2* w  = (const float2*)d_in[0];   // (256,256,256,2) f32 == float2 complex
  const float*  th = (const float*)d_in[1];    // (180,)
  const float*  tl = (const float*)d_in[2];    // scalar
  float2* F    = (float2*)d_ws;                // 256^3 complex64 = 128 MiB
  float2* out2 = (float2*)d_out;               // (180,256,256) complex64 view of output

  // forward 3D FFT (centered), one pass per axis, 65536 lines each
  fft_pass<0, false><<<8192, 256, 0, stream>>>(w, F);   // axis 2 (contiguous)
  fft_pass<1, false><<<8192, 256, 0, stream>>>(F, F);   // axis 1 (stride 256)
  fft_pass<2, false><<<8192, 256, 0, stream>>>(F, F);   // axis 0 (stride 65536)

  // Fourier-slice trilinear sampling -> d_out
  dim3 g(16, 16, 180), blk(16, 16);
  sample_kernel<<<g, blk, 0, stream>>>(F, out2, th, tl);

  // centered inverse 2D FFT per angle, in place in d_out; 180*256 lines per pass
  fft_pass<0, true><<<5760, 256, 0, stream>>>(out2, out2);  // axis b (contiguous)
  fft_pass<1, true><<<5760, 256, 0, stream>>>(out2, out2);  // axis a (stride 256)
}

// Round 3
// 610.031 us; speedup vs baseline: 1.3265x; 1.0444x over previous
//
#include <hip/hip_runtime.h>
#include <math.h>

// Laminography forward projector, fully fused pipeline:
//  (1) centered 3D FFT of complex volume (3 1D passes into d_ws)
//  (2) trilinear Fourier-slice sampling -> d_out (as float2)
//  (3) centered inverse 2D FFT, two in-place passes on d_out
// Centered transform identity (n=256, n/2 even):
//  F[k] = (-1)^k * FFT[ (-1)^x * u[x] ]   per axis, forward and inverse alike.

namespace {

// -------- contiguous-axis pass: 8 lines/block, coalesce along j -------------
template<bool INV>
__global__ __launch_bounds__(256)
void fft_pass0(const float2* in, float2* out) {
  __shared__ float sre[8][265];
  __shared__ float sim[8][265];
  __shared__ float twr[128];
  __shared__ float twi[128];
  const int t = threadIdx.x;
  if (t < 128) {
    const float TWO_PI = 6.28318530717958647692f;
    float ang = (INV ? TWO_PI : -TWO_PI) * ((float)t * (1.0f / 256.0f));
    float s, c;
    sincosf(ang, &s, &c);
    twr[t] = c;
    twi[t] = s;
  }
  const int l = t >> 5;
  const int j0 = t & 31;
  const int lineIdx = (int)blockIdx.x * 8 + l;
  const int base = lineIdx * 256;

  #pragma unroll
  for (int r = 0; r < 8; r++) {
    int j = j0 + 32 * r;
    float2 v = in[base + j];
    float sgn = (j & 1) ? -1.0f : 1.0f;
    sre[l][j] = v.x * sgn;
    sim[l][j] = v.y * sgn;
  }
  __syncthreads();

  const int line = t >> 5;
  const int lane = t & 31;
  #pragma unroll
  for (int s = 0; s < 8; s++) {
    const int half = 128 >> s;
    #pragma unroll
    for (int r = 0; r < 4; r++) {
      int b   = lane + 32 * r;
      int pos = b & (half - 1);
      int grp = b >> (7 - s);
      int i   = (grp << (8 - s)) + pos;
      int j   = i + half;
      float ar = sre[line][i], ai = sim[line][i];
      float br = sre[line][j], bi = sim[line][j];
      sre[line][i] = ar + br;
      sim[line][i] = ai + bi;
      float dr = ar - br, di = ai - bi;
      int mm = pos << s;
      float wr = twr[mm], wi = twi[mm];
      sre[line][j] = dr * wr - di * wi;
      sim[line][j] = dr * wi + di * wr;
    }
    __syncthreads();
  }

  const float scale = INV ? (1.0f / 256.0f) : 1.0f;
  #pragma unroll
  for (int r = 0; r < 8; r++) {
    int j = j0 + 32 * r;
    int rev = (int)(__brev((unsigned)j) >> 24);
    float sgn = (j & 1) ? -scale : scale;
    float2 v;
    v.x = sre[l][rev] * sgn;
    v.y = sim[l][rev] * sgn;
    out[base + j] = v;
  }
}

// -------- strided-axis pass (MODE 1: stride 256, MODE 2: stride 65536) ------
// 16 memory-consecutive lines/block, 512 threads: each 16-lane group touches
// a full 128B cacheline on every global load/store (round-0's 8-line blocks
// used only 64B per line; the other half went to a block on another XCD ->
// ~2x HBM over-fetch).  LDS float2[16][257]: row stride 514 dwords == 2
// (mod 32), so all phases are <=2-way on banks (free).  34KB LDS x 4
// blocks/CU = 32 waves/CU: full occupancy, unlike round-1's 16-wave attempt.
template<int MODE, bool INV>
__global__ __launch_bounds__(512)
void fft_pass_s(const float2* in, float2* out) {
  __shared__ float2 sdata[16][257];
  __shared__ float twr[128];
  __shared__ float twi[128];
  const int t = threadIdx.x;
  if (t < 128) {
    const float TWO_PI = 6.28318530717958647692f;
    float ang = (INV ? TWO_PI : -TWO_PI) * ((float)t * (1.0f / 256.0f));
    float s, c;
    sincosf(ang, &s, &c);
    twr[t] = c;
    twi[t] = s;
  }
  const int l  = t & 15;     // line within block (memory-contiguous) -> coalesce
  const int j0 = t >> 4;     // 0..31
  const int lineIdx = (int)blockIdx.x * 16 + l;
  int base, stride;
  if (MODE == 1) { base = (lineIdx >> 8) * 65536 + (lineIdx & 255); stride = 256;   }
  else           { base = lineIdx;                                  stride = 65536; }

  // load with (-1)^x pre-twiddle (centering)
  #pragma unroll
  for (int r = 0; r < 8; r++) {
    int j = j0 + 32 * r;
    float2 v = in[base + j * stride];
    float sgn = (j & 1) ? -1.0f : 1.0f;
    sdata[l][j] = make_float2(v.x * sgn, v.y * sgn);
  }
  __syncthreads();

  // radix-2 DIF, 8 stages; 32 threads per line, 4 butterflies/thread/stage
  const int line = t >> 5;   // 0..15
  const int lane = t & 31;
  #pragma unroll
  for (int s = 0; s < 8; s++) {
    const int half = 128 >> s;
    #pragma unroll
    for (int r = 0; r < 4; r++) {
      int b   = lane + 32 * r;
      int pos = b & (half - 1);
      int grp = b >> (7 - s);
      int i   = (grp << (8 - s)) + pos;
      int j   = i + half;
      float2 A = sdata[line][i];
      float2 B = sdata[line][j];
      sdata[line][i] = make_float2(A.x + B.x, A.y + B.y);
      float dr = A.x - B.x, di = A.y - B.y;
      int mm = pos << s;
      float wr = twr[mm], wi = twi[mm];
      sdata[line][j] = make_float2(dr * wr - di * wi, dr * wi + di * wr);
    }
    __syncthreads();
  }

  // store: DIF leaves X[bitrev(p)] at p; apply (-1)^k post-twiddle (+ 1/n inv)
  const float scale = INV ? (1.0f / 256.0f) : 1.0f;
  #pragma unroll
  for (int r = 0; r < 8; r++) {
    int j = j0 + 32 * r;
    int rev = (int)(__brev((unsigned)j) >> 24);
    float sgn = (j & 1) ? -scale : scale;
    float2 v = sdata[l][rev];
    out[base + j * stride] = make_float2(v.x * sgn, v.y * sgn);
  }
}

// Fourier-slice trilinear sampling.
// Gather address = (x*256+y)*256+z with z = av*sin(tilt)+128: the memory-
// contiguous axis z tracks the detector 'a' axis (step ~0.84 elem/pixel),
// while the 'b' axis steps x/y by ~1/pixel (512KB / 2KB address jumps).
// So fast lanes run along a; stores transposed through LDS to stay coalesced.
__global__ __launch_bounds__(256)
void sample_kernel(const float2* __restrict__ F, float2* __restrict__ out,
                   const float* __restrict__ theta, const float* __restrict__ tiltp) {
  __shared__ float2 tile[16][18];   // [b_local][a_local], padded
  const int m  = blockIdx.z;
  const int tx = threadIdx.x;
  const int ty = threadIdx.y;
  const int a = blockIdx.x * 16 + tx;   // detector slow axis (kv) -> fast lanes
  const int b = blockIdx.y * 16 + ty;   // detector fast axis (ku)
  float th = theta[m];
  float st, ct;
  sincosf(th, &st, &ct);
  float tl = tiltp[0];
  float sp, cp;
  sincosf(tl, &sp, &cp);
  float bu = (float)(b - 128);
  float av = (float)(a - 128);
  float p0 = bu * ct + av * (-st * cp) + 128.0f;
  float p1 = bu * st + av * (ct * cp) + 128.0f;
  float p2 = av * sp + 128.0f;
  float f0 = floorf(p0), f1 = floorf(p1), f2 = floorf(p2);
  int x0 = (int)f0, y0 = (int)f1, z0 = (int)f2;
  float fx = p0 - f0, fy = p1 - f1, fz = p2 - f2;
  float accr = 0.0f, acci = 0.0f;
  #pragma unroll
  for (int dx = 0; dx < 2; dx++) {
    int x = x0 + dx;
    bool vx = (x >= 0) && (x < 256);
    int xc = min(max(x, 0), 255);
    float wx = dx ? fx : (1.0f - fx);
    #pragma unroll
    for (int dy = 0; dy < 2; dy++) {
      int y = y0 + dy;
      bool vy = vx && (y >= 0) && (y < 256);
      int yc = min(max(y, 0), 255);
      float wxy = wx * (dy ? fy : (1.0f - fy));
      int rowbase = (xc * 256 + yc) * 256;
      #pragma unroll
      for (int dz = 0; dz < 2; dz++) {
        int z = z0 + dz;
        bool v = vy && (z >= 0) && (z < 256);
        int zc = min(max(z, 0), 255);
        float w = v ? wxy * (dz ? fz : (1.0f - fz)) : 0.0f;
        float2 c = F[rowbase + zc];   // clamped gather; masked by w
        accr += w * c.x;
        acci += w * c.y;
      }
    }
  }
  tile[ty][tx] = make_float2(accr, acci);
  __syncthreads();
  const int oa = blockIdx.x * 16 + ty;
  const int ob = blockIdx.y * 16 + tx;
  out[((size_t)m * 256 + oa) * 256 + ob] = tile[tx][ty];
}

}  // namespace

extern "C" void kernel_launch(void* const* d_in, const int* in_sizes, int n_in,
                              void* d_out, int out_size, void* d_ws, size_t ws_size,
                              hipStream_t stream) {
  const float2* w  = (const float2*)d_in[0];   // (256,256,256,2) f32 == float2 complex
  const float*  th = (const float*)d_in[1];    // (180,)
  const float*  tl = (const float*)d_in[2];    // scalar
  float2* F    = (float2*)d_ws;                // 256^3 complex64 = 128 MiB
  float2* out2 = (float2*)d_out;               // (180,256,256) complex64 view of output

  // forward 3D FFT (centered), one pass per axis, 65536 lines each
  fft_pass0<false><<<8192, 256, 0, stream>>>(w, F);          // axis 2 (contiguous)
  fft_pass_s<1, false><<<4096, 512, 0, stream>>>(F, F);      // axis 1 (stride 256)
  fft_pass_s<2, false><<<4096, 512, 0, stream>>>(F, F);      // axis 0 (stride 65536)

  // Fourier-slice trilinear sampling -> d_out
  dim3 g(16, 16, 180), blk(16, 16);
  sample_kernel<<<g, blk, 0, stream>>>(F, out2, th, tl);

  // centered inverse 2D FFT per angle, in place in d_out
  fft_pass0<true><<<5760, 256, 0, stream>>>(out2, out2);     // axis b (contiguous)
  fft_pass_s<1, true><<<2880, 512, 0, stream>>>(out2, out2); // axis a (stride 256)
}

// Round 4
// 523.412 us; speedup vs baseline: 1.5461x; 1.1655x over previous
//
#include <hip/hip_runtime.h>
#include <math.h>

// Laminography forward projector, fully fused pipeline:
//  (1) centered 3D FFT of complex volume (3 1D passes into d_ws)
//  (2) trilinear Fourier-slice sampling -> d_out (as float2)
//  (3) centered inverse 2D FFT, two in-place passes on d_out
// Centered transform identity (n=256, n/2 even):
//  F[k] = (-1)^k * FFT[ (-1)^x * u[x] ]   per axis, forward and inverse alike.
//
// FFT structure: 256 = 16 x 16 two-phase register FFT.
//  x = n1 + 16*n2, k = k2 + 16*k1:
//  X[k2+16k1] = sum_n1 W16^{n1 k1} * [ W256^{n1 k2} * sum_n2 W16^{n2 k2} v[n1+16n2] ]
//  Phase A (thread = n1): 16-pt register FFT over n2, twiddle W256^{n1 k2}, -> LDS
//  Phase B (thread = k2): 16-pt register FFT over n1, -> global.
//  One LDS round-trip (4 KB/line) + ONE barrier, vs 64 KB + 9 barriers for the
//  previous all-LDS radix-2 version (which was LDS-BW/barrier bound at 2.6 TB/s).
//  Centering: (-1)^x = (-1)^{n1} (uniform in phase A), (-1)^k = (-1)^{k2}
//  (uniform in phase B) -> folded into scalar signs.

namespace {

__device__ __forceinline__ void fft16_reg(float (&re)[16], float (&im)[16],
                                          bool inv) {
  // radix-2 DIF, 16 points; input natural order, output bit-reversed.
  // All twiddles are compile-time constants after unrolling.
  const float C16[8] = {1.0f, 0.92387953251128675613f, 0.70710678118654752440f,
                        0.38268343236508977173f, 0.0f, -0.38268343236508977173f,
                        -0.70710678118654752440f, -0.92387953251128675613f};
  const float S16[8] = {0.0f, 0.38268343236508977173f, 0.70710678118654752440f,
                        0.92387953251128675613f, 1.0f, 0.92387953251128675613f,
                        0.70710678118654752440f, 0.38268343236508977173f};
  #pragma unroll
  for (int s = 0; s < 4; s++) {
    const int h = 8 >> s;               // half-size: 8,4,2,1
    #pragma unroll
    for (int g = 0; g < (8 >> (3 - s)); g++) {   // groups: 1,2,4,8
      #pragma unroll
      for (int p = 0; p < h; p++) {
        const int i = g * 2 * h + p;
        const int j = i + h;
        const float ar = re[i], ai = im[i], br = re[j], bi = im[j];
        re[i] = ar + br;
        im[i] = ai + bi;
        const float dr = ar - br, di = ai - bi;
        const int t = p << s;           // twiddle exponent, 0..7
        const float wr = C16[t];
        const float wi = inv ? S16[t] : -S16[t];
        re[j] = dr * wr - di * wi;
        im[j] = dr * wi + di * wr;
      }
    }
  }
}

// MODE 0: contiguous lines (stride 1), lanes run along the line.
// MODE 1: stride 256,   lanes run across 16 memory-consecutive lines.
// MODE 2: stride 65536, lanes run across 16 memory-consecutive lines.
template<int MODE, bool INV>
__global__ __launch_bounds__(256)
void fft_pass(const float2* __restrict__ in, float2* __restrict__ out) {
  // [lin]*273 + n1*17 + k2 (float2).  Row pads (17, 273) keep bank usage at
  // the b64 bandwidth floor for both the phase-A write and phase-B read.
  __shared__ float2 zt[16 * 273];      // 34944 B -> 4 blocks/CU, 16 waves/CU
  const int t  = threadIdx.x;
  const int tx = t & 15;
  const int ty = t >> 4;
  const int idA = (MODE == 0) ? tx : ty;   // n1 in phase A, k2 in phase B
  const int lin = (MODE == 0) ? ty : tx;   // line within block
  const int lineIdx = (int)blockIdx.x * 16 + lin;
  int base, stride;
  if (MODE == 0)      { base = lineIdx * 256;                            stride = 1;     }
  else if (MODE == 1) { base = (lineIdx >> 8) * 65536 + (lineIdx & 255); stride = 256;   }
  else                { base = lineIdx;                                  stride = 65536; }

  const int BR4[16] = {0, 8, 4, 12, 2, 10, 6, 14, 1, 9, 5, 13, 3, 11, 7, 15};

  float re[16], im[16];

  // ---------------- phase A: thread = n1 ----------------
  {
    const float s1 = (idA & 1) ? -1.0f : 1.0f;     // (-1)^x pre-twiddle
    #pragma unroll
    for (int n2 = 0; n2 < 16; n2++) {
      const float2 v = in[base + (idA + 16 * n2) * stride];
      re[n2] = v.x * s1;
      im[n2] = v.y * s1;
    }
    fft16_reg(re, im, INV);
    // inter-stage twiddle W256^{n1*k2} via complex recurrence (one sincosf)
    const float TWO_PI = 6.28318530717958647692f;
    const float ang = (INV ? TWO_PI : -TWO_PI) * ((float)idA * (1.0f / 256.0f));
    float ss, cc;
    sincosf(ang, &ss, &cc);
    float wr = 1.0f, wi = 0.0f;
    #pragma unroll
    for (int k2 = 0; k2 < 16; k2++) {
      const float yr = re[BR4[k2]], yi = im[BR4[k2]];
      zt[lin * 273 + idA * 17 + k2] =
          make_float2(yr * wr - yi * wi, yr * wi + yi * wr);
      const float nwr = wr * cc - wi * ss;
      wi = wr * ss + wi * cc;
      wr = nwr;
    }
  }
  __syncthreads();
  // ---------------- phase B: thread = k2 ----------------
  {
    #pragma unroll
    for (int n1 = 0; n1 < 16; n1++) {
      const float2 z = zt[lin * 273 + n1 * 17 + idA];
      re[n1] = z.x;
      im[n1] = z.y;
    }
    fft16_reg(re, im, INV);
    // (-1)^k post-twiddle + inverse scaling
    const float sOut = ((idA & 1) ? -1.0f : 1.0f) * (INV ? (1.0f / 256.0f) : 1.0f);
    #pragma unroll
    for (int k1 = 0; k1 < 16; k1++) {
      out[base + (idA + 16 * k1) * stride] =
          make_float2(re[BR4[k1]] * sOut, im[BR4[k1]] * sOut);
    }
  }
}

// Fourier-slice trilinear sampling.
// Gather address = (x*256+y)*256+z with z = av*sin(tilt)+128: the memory-
// contiguous axis z tracks the detector 'a' axis (step ~0.84 elem/pixel),
// while the 'b' axis steps x/y by ~1/pixel (512KB / 2KB address jumps).
// So fast lanes run along a; stores transposed through LDS to stay coalesced.
__global__ __launch_bounds__(256)
void sample_kernel(const float2* __restrict__ F, float2* __restrict__ out,
                   const float* __restrict__ theta, const float* __restrict__ tiltp) {
  __shared__ float2 tile[16][18];   // [b_local][a_local], padded
  const int m  = blockIdx.z;
  const int tx = threadIdx.x;
  const int ty = threadIdx.y;
  const int a = blockIdx.x * 16 + tx;   // detector slow axis (kv) -> fast lanes
  const int b = blockIdx.y * 16 + ty;   // detector fast axis (ku)
  float th = theta[m];
  float st, ct;
  sincosf(th, &st, &ct);
  float tl = tiltp[0];
  float sp, cp;
  sincosf(tl, &sp, &cp);
  float bu = (float)(b - 128);
  float av = (float)(a - 128);
  float p0 = bu * ct + av * (-st * cp) + 128.0f;
  float p1 = bu * st + av * (ct * cp) + 128.0f;
  float p2 = av * sp + 128.0f;
  float f0 = floorf(p0), f1 = floorf(p1), f2 = floorf(p2);
  int x0 = (int)f0, y0 = (int)f1, z0 = (int)f2;
  float fx = p0 - f0, fy = p1 - f1, fz = p2 - f2;
  float accr = 0.0f, acci = 0.0f;
  #pragma unroll
  for (int dx = 0; dx < 2; dx++) {
    int x = x0 + dx;
    bool vx = (x >= 0) && (x < 256);
    int xc = min(max(x, 0), 255);
    float wx = dx ? fx : (1.0f - fx);
    #pragma unroll
    for (int dy = 0; dy < 2; dy++) {
      int y = y0 + dy;
      bool vy = vx && (y >= 0) && (y < 256);
      int yc = min(max(y, 0), 255);
      float wxy = wx * (dy ? fy : (1.0f - fy));
      int rowbase = (xc * 256 + yc) * 256;
      #pragma unroll
      for (int dz = 0; dz < 2; dz++) {
        int z = z0 + dz;
        bool v = vy && (z >= 0) && (z < 256);
        int zc = min(max(z, 0), 255);
        float w = v ? wxy * (dz ? fz : (1.0f - fz)) : 0.0f;
        float2 c = F[rowbase + zc];   // clamped gather; masked by w
        accr += w * c.x;
        acci += w * c.y;
      }
    }
  }
  tile[ty][tx] = make_float2(accr, acci);
  __syncthreads();
  const int oa = blockIdx.x * 16 + ty;
  const int ob = blockIdx.y * 16 + tx;
  out[((size_t)m * 256 + oa) * 256 + ob] = tile[tx][ty];
}

}  // namespace

extern "C" void kernel_launch(void* const* d_in, const int* in_sizes, int n_in,
                              void* d_out, int out_size, void* d_ws, size_t ws_size,
                              hipStream_t stream) {
  const float2* w  = (const float2*)d_in[0];   // (256,256,256,2) f32 == float2 complex
  const float*  th = (const float*)d_in[1];    // (180,)
  const float*  tl = (const float*)d_in[2];    // scalar
  float2* F    = (float2*)d_ws;                // 256^3 complex64 = 128 MiB
  float2* out2 = (float2*)d_out;               // (180,256,256) complex64 view of output

  // forward 3D FFT (centered), one pass per axis, 65536 lines each (16/block)
  fft_pass<0, false><<<4096, 256, 0, stream>>>(w, F);   // axis 2 (contiguous)
  fft_pass<1, false><<<4096, 256, 0, stream>>>(F, F);   // axis 1 (stride 256)
  fft_pass<2, false><<<4096, 256, 0, stream>>>(F, F);   // axis 0 (stride 65536)

  // Fourier-slice trilinear sampling -> d_out
  dim3 g(16, 16, 180), blk(16, 16);
  sample_kernel<<<g, blk, 0, stream>>>(F, out2, th, tl);

  // centered inverse 2D FFT per angle, in place in d_out; 46080 lines per pass
  fft_pass<0, true><<<2880, 256, 0, stream>>>(out2, out2);  // axis b (contiguous)
  fft_pass<1, true><<<2880, 256, 0, stream>>>(out2, out2);  // axis a (stride 256)
}